// Round 9
// baseline (309.779 us; speedup 1.0000x reference)
//
#include <hip/hip_runtime.h>
#include <math.h>

#define Hh 24
#define Ww 24
#define Nn 576
#define Dd 1024
#define Bb 32
#define Kk 256
#define Mm 128
#define TOKSTRIDE (577 * 1024)

// Per-batch scratch lives INSIDE d_out: batch b owns out[b*Mm*Dd .. (b+1)*Mm*Dd).
// Scratch is consumed (via LDS/regs) before the plan/output phases overwrite
// the rows. d_ws holds two spin counters (zeroed by hipMemsetAsync each call).
#define R0_OFF 0       // roots0           : 576 int
#define P_OFF 2944     // p = patch.u      : 576 float
#define QC_OFF 3776    // qcls             : 1024 float
#define U_OFF 4800     // u = qcls.v_w     : 1024 float
#define T_OFF 5824     // t = qcls.v_b     : 1 float

__device__ __forceinline__ float* batch_base(float* out, int b) {
  return out + (size_t)b * Mm * Dd;
}

// Full-wave (64-lane) float sum via DPP — VALU pipe only, no LDS traffic.
__device__ __forceinline__ float wave_sum_dpp(float x) {
  int y;
  y = __builtin_amdgcn_update_dpp(0, __float_as_int(x), 0x111, 0xf, 0xf, true);
  x += __int_as_float(y);  // row_shr:1
  y = __builtin_amdgcn_update_dpp(0, __float_as_int(x), 0x112, 0xf, 0xf, true);
  x += __int_as_float(y);  // row_shr:2
  y = __builtin_amdgcn_update_dpp(0, __float_as_int(x), 0x114, 0xf, 0xf, true);
  x += __int_as_float(y);  // row_shr:4
  y = __builtin_amdgcn_update_dpp(0, __float_as_int(x), 0x118, 0xf, 0xf, true);
  x += __int_as_float(y);  // row_shr:8  -> lanes 15/31/47/63 hold row sums
  y = __builtin_amdgcn_update_dpp(0, __float_as_int(x), 0x142, 0xa, 0xf, true);
  x += __int_as_float(y);  // row_bcast:15 into rows 1,3
  y = __builtin_amdgcn_update_dpp(0, __float_as_int(x), 0x143, 0xc, 0xf, true);
  x += __int_as_float(y);  // row_bcast:31 into rows 2,3 -> lane 63 = total
  return x;
}

// 16-lane row sum via DPP (4 stages). Lanes 15/31/47/63 hold their row's sum.
__device__ __forceinline__ float row_sum_dpp(float x) {
  int y;
  y = __builtin_amdgcn_update_dpp(0, __float_as_int(x), 0x111, 0xf, 0xf, true);
  x += __int_as_float(y);  // row_shr:1
  y = __builtin_amdgcn_update_dpp(0, __float_as_int(x), 0x112, 0xf, 0xf, true);
  x += __int_as_float(y);  // row_shr:2
  y = __builtin_amdgcn_update_dpp(0, __float_as_int(x), 0x114, 0xf, 0xf, true);
  x += __int_as_float(y);  // row_shr:4
  y = __builtin_amdgcn_update_dpp(0, __float_as_int(x), 0x118, 0xf, 0xf, true);
  x += __int_as_float(y);  // row_shr:8
  return x;
}

// --- spin-barrier helpers (co-resident blocks only; G16-safe: no dispatch-
//     order assumption — ALL blocks of the fused grid fit on-chip at once) ---
__device__ __forceinline__ void publish_done(unsigned int* c) {
  // call AFTER __syncthreads(): pre-barrier vmcnt drain has pushed all block
  // stores to L2; threadfence (buffer_wbl2, device scope) makes them visible
  // across XCDs before the counter increment.
  if (threadIdx.x == 0) {
    __threadfence();
    atomicAdd(c, 1u);  // device-scope by default on CDNA
  }
}
__device__ __forceinline__ void wait_done(unsigned int* c, unsigned int tgt) {
  if (threadIdx.x == 0) {
    while (__hip_atomic_load(c, __ATOMIC_RELAXED, __HIP_MEMORY_SCOPE_AGENT) <
           tgt)
      __builtin_amdgcn_s_sleep(8);
    __threadfence();  // acquire: invalidate L1/L2 (stale lines from prev replay)
  }
  __syncthreads();
}

// ---------------------------------------------------------------------------
// A (fused qcls + u_t, one launch): blocks 0..1023 = qcls role (verbatim r8
//     qcls body, dp = blockIdx); blocks 1024..1279 = ut role (verbatim r8
//     u_t body), which first waits for cnt[0]==1024. 1280 blocks x 4 waves
//     = 5120 waves <= 8192 chip capacity -> all co-resident -> deadlock-free.
// ---------------------------------------------------------------------------
__global__ __launch_bounds__(256) void qcls_ut_fused(
    const float* __restrict__ tok2d, const float* __restrict__ q_w,
    const float* __restrict__ q_b, const float* __restrict__ v_w,
    const float* __restrict__ v_b, float* __restrict__ outb,
    unsigned int* __restrict__ cnt) {
  __shared__ float qs[Dd];
  __shared__ float4 part[8][32];
  __shared__ float sh[256];
  int tid = threadIdx.x;

  if (blockIdx.x < 1024) {
    // ---- qcls role ----
    int dp = blockIdx.x;
    int wave = tid >> 6;
    int lane = tid & 63;
    float4 qv[4];
#pragma unroll
    for (int i = 0; i < 4; i++)
      qv[i] = *(const float4*)(q_w + (size_t)dp * Dd + lane * 4 + 256 * i);
    float qb = q_b[dp];
#pragma unroll 2
    for (int bb = 0; bb < 8; bb++) {
      int b = wave * 8 + bb;
      const float* cls = tok2d + (size_t)b * TOKSTRIDE;
      float a = 0.f;
#pragma unroll
      for (int i = 0; i < 4; i++) {
        float4 cv = *(const float4*)(cls + lane * 4 + 256 * i);
        a += qv[i].x * cv.x + qv[i].y * cv.y + qv[i].z * cv.z + qv[i].w * cv.w;
      }
      a = wave_sum_dpp(a);
      if (lane == 63) batch_base(outb, b)[QC_OFF + dp] = a + qb;
    }
    __syncthreads();
    publish_done(&cnt[0]);
    return;
  }

  // ---- ut role ----
  wait_done(&cnt[0], 1024u);
  int idx = blockIdx.x - 1024;
  int b = idx >> 3;
  int s = idx & 7;
  int dl = tid & 31;
  int g = tid >> 5;
  float* basef = batch_base(outb, b);
  for (int i = tid; i < Dd; i += 256) qs[i] = basef[QC_OFF + i];
  __syncthreads();
  int d0 = s * 128 + dl * 4;
  float4 a = make_float4(0.f, 0.f, 0.f, 0.f);
#pragma unroll 4
  for (int dpl = 0; dpl < 128; dpl++) {
    int dp = g * 128 + dpl;
    float4 vv = *(const float4*)(v_w + (size_t)dp * Dd + d0);
    float qq = qs[dp];
    a.x += qq * vv.x; a.y += qq * vv.y; a.z += qq * vv.z; a.w += qq * vv.w;
  }
  part[g][dl] = a;
  __syncthreads();
  if (tid < 32) {
    // left-fold ascending g — identical FP order to combine_ut's c-loop
    float4 u = make_float4(0.f, 0.f, 0.f, 0.f);
#pragma unroll
    for (int c = 0; c < 8; c++) {
      float4 v = part[c][tid];
      u.x += v.x; u.y += v.y; u.z += v.z; u.w += v.w;
    }
    *(float4*)(basef + U_OFF + s * 128 + tid * 4) = u;
  }
  if (s == 0) {  // t, verbatim combine_ut pattern
    float aa = 0.f;
    for (int i = tid; i < Dd; i += 256) aa += qs[i] * v_b[i];
    sh[tid] = aa;
    __syncthreads();
    for (int st = 128; st > 0; st >>= 1) {
      if (tid < st) sh[tid] += sh[tid + st];
      __syncthreads();
    }
    if (tid == 0) basef[T_OFF] = sh[0];
  }
}

// ---------------------------------------------------------------------------
// K1 v6 (r6/r8 proven, ~50 µs): fused affinity + p. Unchanged.
// ---------------------------------------------------------------------------
__global__ __launch_bounds__(256, 3) void affinity_p_root_kernel(
    const float* __restrict__ tok2d, const float* __restrict__ dw_w,
    const float* __restrict__ pw_w, const float* __restrict__ pw_b,
    float* __restrict__ outb) {
  int wave = threadIdx.x >> 6;  // d-chunk
  int lane = threadIdx.x & 63;
  // XCD-aware bijective swizzle: 2304 blocks = 8 XCDs * 288 contiguous ids.
  int blk = (blockIdx.x & 7) * (Bb * Hh * 3 / 8) + (blockIdx.x >> 3);
  int b = blk / (Hh * 3);
  int rem = blk % (Hh * 3);
  int y = rem / 3;
  int x0 = (rem % 3) * 8;
  int d0 = wave * 256 + lane * 4;
  const float* patch = tok2d + (size_t)b * TOKSTRIDE + Dd;  // skip cls token
  float* basef = batch_base(outb, b);

  __shared__ float red[8 * 167 + 8];

  union { float4 v[9]; float f[36]; } w;
  const float4* dwp = (const float4*)(dw_w + (size_t)d0 * 9);
#pragma unroll
  for (int j = 0; j < 9; j++) w.v[j] = dwp[j];
  float4 u4 = *(const float4*)(basef + U_OFF + d0);

  float4 cc[8];
  float pacc[8];
#pragma unroll
  for (int t = 0; t < 8; t++) {
    cc[t] = make_float4(0.f, 0.f, 0.f, 0.f);
    pacc[t] = 0.f;
  }
#pragma unroll
  for (int ky = 0; ky < 3; ky++) {
    int yy = y + ky - 1;
    if (yy < 0 || yy >= Hh) continue;  // wave-uniform (zero padding)
    const float* prow = patch + (size_t)(yy * Ww) * Dd + d0;
    float4 wrow[10];
    wrow[0] = make_float4(0.f, 0.f, 0.f, 0.f);
    if (x0 > 0) wrow[0] = *(const float4*)(prow + (size_t)(x0 - 1) * Dd);
#pragma unroll
    for (int j = 1; j < 9; j++)
      wrow[j] = *(const float4*)(prow + (size_t)(x0 - 1 + j) * Dd);
    wrow[9] = make_float4(0.f, 0.f, 0.f, 0.f);
    if (x0 + 8 < Ww) wrow[9] = *(const float4*)(prow + (size_t)(x0 + 8) * Dd);
    int kA = ky * 3, kB = ky * 3 + 1, kC = ky * 3 + 2;
#pragma unroll
    for (int t = 0; t < 8; t++) {
      cc[t].x += wrow[t].x * w.f[kA] + wrow[t + 1].x * w.f[kB] +
                 wrow[t + 2].x * w.f[kC];
      cc[t].y += wrow[t].y * w.f[9 + kA] + wrow[t + 1].y * w.f[9 + kB] +
                 wrow[t + 2].y * w.f[9 + kC];
      cc[t].z += wrow[t].z * w.f[18 + kA] + wrow[t + 1].z * w.f[18 + kB] +
                 wrow[t + 2].z * w.f[18 + kC];
      cc[t].w += wrow[t].w * w.f[27 + kA] + wrow[t + 1].w * w.f[27 + kB] +
                 wrow[t + 2].w * w.f[27 + kC];
      if (ky == 1)
        pacc[t] = wrow[t + 1].x * u4.x + wrow[t + 1].y * u4.y +
                  wrow[t + 1].z * u4.z + wrow[t + 1].w * u4.w;
    }
  }

  __builtin_amdgcn_sched_barrier(0);

  float4 pw[9];
#pragma unroll
  for (int o = 0; o < 9; o++)
    pw[o] = *(const float4*)(pw_w + (size_t)o * Dd + d0);

#pragma unroll
  for (int t = 0; t < 8; t++) {
    float acc[10];
#pragma unroll
    for (int o = 0; o < 9; o++) {
      acc[o] = cc[t].x * pw[o].x + cc[t].y * pw[o].y + cc[t].z * pw[o].z +
               cc[t].w * pw[o].w;
    }
    acc[9] = pacc[t];
#pragma unroll
    for (int o = 0; o < 10; o++) acc[o] = row_sum_dpp(acc[o]);
    if ((lane & 15) == 15) {
      int r = wave * 4 + (lane >> 4);
#pragma unroll
      for (int o = 0; o < 10; o++) red[t * 167 + r * 10 + o] = acc[o];
    }
  }
  __syncthreads();

  if (lane < 2) {
    int t = wave * 2 + lane;
    int x = x0 + t;
    int n = y * Ww + x;
    float l[10];
#pragma unroll
    for (int o = 0; o < 10; o++) l[o] = 0.f;
    for (int r = 0; r < 16; r++) {
#pragma unroll
      for (int o = 0; o < 10; o++) l[o] += red[t * 167 + r * 10 + o];
    }
    float q[9];
    float mx = -INFINITY;
#pragma unroll
    for (int o = 0; o < 9; o++) {
      l[o] += pw_b[o];
      mx = fmaxf(mx, l[o]);
    }
    float ssum = 0.f;
#pragma unroll
    for (int o = 0; o < 9; o++) {
      q[o] = expf(l[o] - mx);
      ssum += q[o];
    }
#pragma unroll
    for (int o = 0; o < 9; o++) q[o] = q[o] / ssum;

    int colv[9];
#pragma unroll
    for (int o = 0; o < 9; o++) {
      int dy = o / 3 - 1, dx = o % 3 - 1;
      int ny = min(max(y + dy, 0), Hh - 1);
      int nx = min(max(x + dx, 0), Ww - 1);
      colv[o] = ny * Ww + nx;
    }
    float best = -1.f;
    int bcol = 1 << 30;
#pragma unroll
    for (int o = 0; o < 9; o++) {
      float v = 0.f;
#pragma unroll
      for (int oo = 0; oo < 9; oo++)
        v = (colv[oo] == colv[o]) ? v + q[oo] : v;
      if (v > best || (v == best && colv[o] < bcol)) {
        best = v;
        bcol = colv[o];
      }
    }
    ((int*)basef)[R0_OFF + n] = bcol;
    basef[P_OFF + n] = l[9];
  }
}

// ---------------------------------------------------------------------------
// B (fused csp + output, one launch): blocks 0..31 = csp role (verbatim r8
//     cluster_scores_plan body), publish cnt[1]. Blocks 32..543 = output
//     role: wait cnt[1]==32, then 8 rows each (512 lanes x float2; each
//     element still accumulated in ascending member order -> bitwise
//     identical to the old per-row kernel). 544 blocks x 9 waves = 4896
//     waves <= 8192 -> all co-resident -> deadlock-free.
// ---------------------------------------------------------------------------
__global__ __launch_bounds__(576) void csp_out_fused(
    const float* __restrict__ tok2d, float* __restrict__ outb,
    unsigned int* __restrict__ cnt) {
  __shared__ int ra[Nn], rb2[Nn], scnt[Nn], soff[Nn], smem[Nn];
  __shared__ float sp[Nn];
  __shared__ int s_ord[Kk], s_cnt[Kk], sel[Kk], s_out[Mm];
  __shared__ float ss[Kk];
  __shared__ int s_c;
  int n = threadIdx.x;

  if (blockIdx.x < 32) {
    // ---- csp role ----
    int b = blockIdx.x;
    float* basef = batch_base(outb, b);
    int* base = (int*)basef;
    ra[n] = base[R0_OFF + n];
    sp[n] = basef[P_OFF + n];
    scnt[n] = 0;
    __syncthreads();
    for (int it = 0; it < 6; it++) {
      rb2[n] = ra[ra[n]];
      __syncthreads();
      ra[n] = rb2[n];
      __syncthreads();
    }
    int r = ra[n];
    atomicAdd(&scnt[r], 1);
    __syncthreads();

    soff[n] = scnt[n];
    __syncthreads();
    for (int s = 1; s < Nn; s <<= 1) {
      int v = (n >= s) ? soff[n - s] : 0;
      __syncthreads();
      soff[n] += v;
      __syncthreads();
    }
    int offr = soff[r] - scnt[r];
    int rk = 0;
    for (int m = 0; m < n; m++) rk += (ra[m] == r);
    smem[offr + rk] = n;

    int cn = scnt[n];
    int rank = 0;
    for (int m = 0; m < Nn; m++) {
      int cm = scnt[m];
      rank += (cm > cn) || (cm == cn && m < n);
    }
    int sl = (rank < Kk) ? 1 : 0;
    rb2[n] = sl;
    __syncthreads();
    for (int s = 1; s < Nn; s <<= 1) {
      int v = (n >= s) ? rb2[n - s] : 0;
      __syncthreads();
      rb2[n] += v;
      __syncthreads();
    }
    if (sl) {
      int pos = rb2[n] - 1;
      s_ord[pos] = n;
      s_cnt[pos] = cn;
    }
    __syncthreads();

    if (n < Kk) {
      int idx = s_ord[n];
      int c = s_cnt[n];
      float s;
      if (c > 0) {
        int off = soff[idx] - scnt[idx];
        float sum = 0.f;
        for (int j = 0; j < c; j++) sum += sp[smem[off + j]];
        s = (sum / (float)c + basef[T_OFF]) * (1.0f / 32.0f);
      } else {
        s = -INFINITY;
      }
      ss[n] = s;
    }
    __syncthreads();

    if (n < Kk) {
      float vk = ss[n];
      int rank2 = 0;
      for (int m = 0; m < Kk; m++) {
        float vm = ss[m];
        rank2 += (vm > vk) || (vm == vk && m < n);
      }
      sel[n] = (rank2 < Mm) ? 1 : 0;
    }
    __syncthreads();
    if (n < Kk && sel[n]) {
      int pos = 0;
      for (int m = 0; m < n; m++) pos += sel[m];
      s_out[pos] = n;
    }
    __syncthreads();

    int w9 = n >> 6, lane = n & 63;
    for (int kp = w9; kp < Mm; kp += 9) {
      int k = s_out[kp];
      int kidx = s_ord[k];
      int kc = s_cnt[k];
      int koff = soff[kidx] - scnt[kidx];
      int* row = base + kp * Dd;
      if (lane == 0) row[0] = kc;
      for (int j = lane; j < kc; j += 64) row[1 + j] = smem[koff + j];
    }
    __syncthreads();
    publish_done(&cnt[1]);
    return;
  }

  // ---- output role: 8 rows per block ----
  wait_done(&cnt[1], 32u);
  int base_row = (blockIdx.x - 32) * 8;  // rows of one batch (8 | 128)
  int b = base_row >> 7;
  const float* patch = tok2d + (size_t)b * TOKSTRIDE + Dd;
  for (int rr = 0; rr < 8; rr++) {
    int row = base_row + rr;
    float* rowf = outb + (size_t)row * Dd;
    int* rowi = (int*)rowf;
    if (n == 0) s_c = rowi[0];
    __syncthreads();
    int c = s_c;
    for (int j = n; j < c; j += 576) smem[j] = rowi[1 + j];
    __syncthreads();
    if (n < 512) {
      int d0 = n * 2;
      float2 acc = make_float2(0.f, 0.f);
      for (int j = 0; j < c; j++) {
        float2 rv = *(const float2*)(patch + (size_t)smem[j] * Dd + d0);
        acc.x += rv.x;
        acc.y += rv.y;
      }
      float inv = 1.0f / (float)max(c, 1);
      *(float2*)(rowf + d0) = make_float2(acc.x * inv, acc.y * inv);
    }
    __syncthreads();  // smem/s_c reused next row
  }
}

// ---------------------------------------------------------------------------
// Fallback kernels (r8-proven) — used only if ws_size < 64.
// ---------------------------------------------------------------------------
__global__ __launch_bounds__(256) void qcls_kernel(
    const float* __restrict__ tok2d, const float* __restrict__ q_w,
    const float* __restrict__ q_b, float* __restrict__ outb) {
  int dp = blockIdx.x;
  int wave = threadIdx.x >> 6;
  int lane = threadIdx.x & 63;
  float4 qv[4];
#pragma unroll
  for (int i = 0; i < 4; i++)
    qv[i] = *(const float4*)(q_w + (size_t)dp * Dd + lane * 4 + 256 * i);
  float qb = q_b[dp];
#pragma unroll 2
  for (int bb = 0; bb < 8; bb++) {
    int b = wave * 8 + bb;
    const float* cls = tok2d + (size_t)b * TOKSTRIDE;
    float a = 0.f;
#pragma unroll
    for (int i = 0; i < 4; i++) {
      float4 cv = *(const float4*)(cls + lane * 4 + 256 * i);
      a += qv[i].x * cv.x + qv[i].y * cv.y + qv[i].z * cv.z + qv[i].w * cv.w;
    }
    a = wave_sum_dpp(a);
    if (lane == 63) batch_base(outb, b)[QC_OFF + dp] = a + qb;
  }
}

__global__ __launch_bounds__(256) void u_t_kernel(const float* __restrict__ v_w,
                                                  const float* __restrict__ v_b,
                                                  float* __restrict__ outb) {
  int b = blockIdx.x >> 3;
  int s = blockIdx.x & 7;
  int tid = threadIdx.x;
  int dl = tid & 31;
  int g = tid >> 5;
  float* basef = batch_base(outb, b);
  __shared__ float qs[Dd];
  __shared__ float4 part[8][32];
  __shared__ float sh[256];
  for (int i = tid; i < Dd; i += 256) qs[i] = basef[QC_OFF + i];
  __syncthreads();
  int d0 = s * 128 + dl * 4;
  float4 a = make_float4(0.f, 0.f, 0.f, 0.f);
#pragma unroll 4
  for (int dpl = 0; dpl < 128; dpl++) {
    int dp = g * 128 + dpl;
    float4 vv = *(const float4*)(v_w + (size_t)dp * Dd + d0);
    float qq = qs[dp];
    a.x += qq * vv.x; a.y += qq * vv.y; a.z += qq * vv.z; a.w += qq * vv.w;
  }
  part[g][dl] = a;
  __syncthreads();
  if (tid < 32) {
    float4 u = make_float4(0.f, 0.f, 0.f, 0.f);
#pragma unroll
    for (int c = 0; c < 8; c++) {
      float4 v = part[c][tid];
      u.x += v.x; u.y += v.y; u.z += v.z; u.w += v.w;
    }
    *(float4*)(basef + U_OFF + s * 128 + tid * 4) = u;
  }
  if (s == 0) {
    float aa = 0.f;
    for (int i = tid; i < Dd; i += 256) aa += qs[i] * v_b[i];
    sh[tid] = aa;
    __syncthreads();
    for (int st = 128; st > 0; st >>= 1) {
      if (tid < st) sh[tid] += sh[tid + st];
      __syncthreads();
    }
    if (tid == 0) basef[T_OFF] = sh[0];
  }
}

__global__ __launch_bounds__(576) void cluster_scores_plan_kernel(
    float* __restrict__ outb) {
  int b = blockIdx.x;
  int n = threadIdx.x;
  float* basef = batch_base(outb, b);
  int* base = (int*)basef;
  __shared__ int ra[Nn], rb2[Nn], scnt[Nn], soff[Nn], smem[Nn];
  __shared__ float sp[Nn];
  __shared__ int s_ord[Kk], s_cnt[Kk], sel[Kk], s_out[Mm];
  __shared__ float ss[Kk];
  ra[n] = base[R0_OFF + n];
  sp[n] = basef[P_OFF + n];
  scnt[n] = 0;
  __syncthreads();
  for (int it = 0; it < 6; it++) {
    rb2[n] = ra[ra[n]];
    __syncthreads();
    ra[n] = rb2[n];
    __syncthreads();
  }
  int r = ra[n];
  atomicAdd(&scnt[r], 1);
  __syncthreads();
  soff[n] = scnt[n];
  __syncthreads();
  for (int s = 1; s < Nn; s <<= 1) {
    int v = (n >= s) ? soff[n - s] : 0;
    __syncthreads();
    soff[n] += v;
    __syncthreads();
  }
  int offr = soff[r] - scnt[r];
  int rk = 0;
  for (int m = 0; m < n; m++) rk += (ra[m] == r);
  smem[offr + rk] = n;
  int cn = scnt[n];
  int rank = 0;
  for (int m = 0; m < Nn; m++) {
    int cm = scnt[m];
    rank += (cm > cn) || (cm == cn && m < n);
  }
  int sl = (rank < Kk) ? 1 : 0;
  rb2[n] = sl;
  __syncthreads();
  for (int s = 1; s < Nn; s <<= 1) {
    int v = (n >= s) ? rb2[n - s] : 0;
    __syncthreads();
    rb2[n] += v;
    __syncthreads();
  }
  if (sl) {
    int pos = rb2[n] - 1;
    s_ord[pos] = n;
    s_cnt[pos] = cn;
  }
  __syncthreads();
  if (n < Kk) {
    int idx = s_ord[n];
    int c = s_cnt[n];
    float s;
    if (c > 0) {
      int off = soff[idx] - scnt[idx];
      float sum = 0.f;
      for (int j = 0; j < c; j++) sum += sp[smem[off + j]];
      s = (sum / (float)c + basef[T_OFF]) * (1.0f / 32.0f);
    } else {
      s = -INFINITY;
    }
    ss[n] = s;
  }
  __syncthreads();
  if (n < Kk) {
    float vk = ss[n];
    int rank2 = 0;
    for (int m = 0; m < Kk; m++) {
      float vm = ss[m];
      rank2 += (vm > vk) || (vm == vk && m < n);
    }
    sel[n] = (rank2 < Mm) ? 1 : 0;
  }
  __syncthreads();
  if (n < Kk && sel[n]) {
    int pos = 0;
    for (int m = 0; m < n; m++) pos += sel[m];
    s_out[pos] = n;
  }
  __syncthreads();
  int w9 = n >> 6, lane = n & 63;
  for (int kp = w9; kp < Mm; kp += 9) {
    int k = s_out[kp];
    int kidx = s_ord[k];
    int kc = s_cnt[k];
    int koff = soff[kidx] - scnt[kidx];
    int* row = base + kp * Dd;
    if (lane == 0) row[0] = kc;
    for (int j = lane; j < kc; j += 64) row[1 + j] = smem[koff + j];
  }
}

__global__ __launch_bounds__(256) void output_kernel(
    const float* __restrict__ tok2d, float* __restrict__ outb) {
  int blk = blockIdx.x;
  int b = blk / Mm;
  int tid = threadIdx.x;
  float* rowf = outb + (size_t)blk * Dd;
  int* rowi = (int*)rowf;
  __shared__ int s_c;
  __shared__ int s_m[Nn];
  if (tid == 0) s_c = rowi[0];
  __syncthreads();
  int c = s_c;
  for (int j = tid; j < c; j += 256) s_m[j] = rowi[1 + j];
  __syncthreads();
  const float* patch = tok2d + (size_t)b * TOKSTRIDE + Dd;
  int d0 = tid * 4;
  float4 acc = make_float4(0.f, 0.f, 0.f, 0.f);
  for (int j = 0; j < c; j++) {
    float4 rv = *(const float4*)(patch + (size_t)s_m[j] * Dd + d0);
    acc.x += rv.x; acc.y += rv.y; acc.z += rv.z; acc.w += rv.w;
  }
  float inv = 1.0f / (float)max(c, 1);
  *(float4*)(rowf + d0) =
      make_float4(acc.x * inv, acc.y * inv, acc.z * inv, acc.w * inv);
}

// ---------------------------------------------------------------------------
extern "C" void kernel_launch(void* const* d_in, const int* in_sizes, int n_in,
                              void* d_out, int out_size, void* d_ws,
                              size_t ws_size, hipStream_t stream) {
  const float* tok2d = (const float*)d_in[0];
  const float* dw_w = (const float*)d_in[1];
  const float* pw_w = (const float*)d_in[2];
  const float* pw_b = (const float*)d_in[3];
  const float* q_w = (const float*)d_in[4];
  const float* q_b = (const float*)d_in[5];
  const float* v_w = (const float*)d_in[6];
  const float* v_b = (const float*)d_in[7];
  float* out = (float*)d_out;

  if (ws_size >= 64) {
    unsigned int* cnt = (unsigned int*)d_ws;
    hipMemsetAsync(d_ws, 0, 64, stream);  // zero spin counters each replay
    qcls_ut_fused<<<dim3(1280), dim3(256), 0, stream>>>(tok2d, q_w, q_b, v_w,
                                                        v_b, out, cnt);
    affinity_p_root_kernel<<<dim3(Bb * Hh * 3), dim3(256), 0, stream>>>(
        tok2d, dw_w, pw_w, pw_b, out);
    csp_out_fused<<<dim3(32 + 512), dim3(576), 0, stream>>>(tok2d, out, cnt);
  } else {
    // fallback: r8-proven 5-kernel path
    qcls_kernel<<<dim3(Dd), dim3(256), 0, stream>>>(tok2d, q_w, q_b, out);
    u_t_kernel<<<dim3(Bb * 8), dim3(256), 0, stream>>>(v_w, v_b, out);
    affinity_p_root_kernel<<<dim3(Bb * Hh * 3), dim3(256), 0, stream>>>(
        tok2d, dw_w, pw_w, pw_b, out);
    cluster_scores_plan_kernel<<<dim3(Bb), dim3(Nn), 0, stream>>>(out);
    output_kernel<<<dim3(Bb * Mm), dim3(256), 0, stream>>>(tok2d, out);
  }
}

// Round 10
// 241.193 us; speedup vs baseline: 1.2844x; 1.2844x over previous
//
#include <hip/hip_runtime.h>
#include <math.h>

#define Hh 24
#define Ww 24
#define Nn 576
#define Dd 1024
#define Bb 32
#define Kk 256
#define Mm 128
#define TOKSTRIDE (577 * 1024)

// Per-batch scratch lives INSIDE d_out: batch b owns out[b*Mm*Dd .. (b+1)*Mm*Dd).
// Scratch is consumed (via LDS/regs) before the plan/output phases overwrite
// the rows. d_ws is NOT used. (r7: cooperative launch breaks graph capture;
// r9: spin-barrier fusion costs more than the launch it saves — kernel
// boundaries are the cheapest grid-wide sync on this harness.)
#define R0_OFF 0       // roots0           : 576 int
#define P_OFF 2944     // p = patch.u      : 576 float
#define QC_OFF 3776    // qcls             : 1024 float
#define U_OFF 4800     // u = qcls.v_w     : 1024 float
#define T_OFF 5824     // t = qcls.v_b     : 1 float

__device__ __forceinline__ float* batch_base(float* out, int b) {
  return out + (size_t)b * Mm * Dd;
}

// Full-wave (64-lane) float sum via DPP — VALU pipe only, no LDS traffic.
// Canonical gfx9/CDNA sequence; result valid in lane 63.
__device__ __forceinline__ float wave_sum_dpp(float x) {
  int y;
  y = __builtin_amdgcn_update_dpp(0, __float_as_int(x), 0x111, 0xf, 0xf, true);
  x += __int_as_float(y);  // row_shr:1
  y = __builtin_amdgcn_update_dpp(0, __float_as_int(x), 0x112, 0xf, 0xf, true);
  x += __int_as_float(y);  // row_shr:2
  y = __builtin_amdgcn_update_dpp(0, __float_as_int(x), 0x114, 0xf, 0xf, true);
  x += __int_as_float(y);  // row_shr:4
  y = __builtin_amdgcn_update_dpp(0, __float_as_int(x), 0x118, 0xf, 0xf, true);
  x += __int_as_float(y);  // row_shr:8  -> lanes 15/31/47/63 hold row sums
  y = __builtin_amdgcn_update_dpp(0, __float_as_int(x), 0x142, 0xa, 0xf, true);
  x += __int_as_float(y);  // row_bcast:15 into rows 1,3
  y = __builtin_amdgcn_update_dpp(0, __float_as_int(x), 0x143, 0xc, 0xf, true);
  x += __int_as_float(y);  // row_bcast:31 into rows 2,3 -> lane 63 = total
  return x;
}

// 16-lane row sum via DPP (4 stages). Lanes 15/31/47/63 hold their row's sum.
__device__ __forceinline__ float row_sum_dpp(float x) {
  int y;
  y = __builtin_amdgcn_update_dpp(0, __float_as_int(x), 0x111, 0xf, 0xf, true);
  x += __int_as_float(y);  // row_shr:1
  y = __builtin_amdgcn_update_dpp(0, __float_as_int(x), 0x112, 0xf, 0xf, true);
  x += __int_as_float(y);  // row_shr:2
  y = __builtin_amdgcn_update_dpp(0, __float_as_int(x), 0x114, 0xf, 0xf, true);
  x += __int_as_float(y);  // row_shr:4
  y = __builtin_amdgcn_update_dpp(0, __float_as_int(x), 0x118, 0xf, 0xf, true);
  x += __int_as_float(y);  // row_shr:8
  return x;
}

// ---------------------------------------------------------------------------
// K4 (runs FIRST): qcls[b,dp] = cls[b]·q_w[dp,:] + q_b[dp]. One block per dp;
//     4 waves, each handles 8 batches (q_w row reused in regs). r7 lesson:
//     this 4096-wave geometry is 4x the coop variant's parallelism — keep it.
// ---------------------------------------------------------------------------
__global__ __launch_bounds__(256) void qcls_kernel(
    const float* __restrict__ tok2d, const float* __restrict__ q_w,
    const float* __restrict__ q_b, float* __restrict__ outb) {
  int dp = blockIdx.x;
  int wave = threadIdx.x >> 6;
  int lane = threadIdx.x & 63;
  float4 qv[4];
#pragma unroll
  for (int i = 0; i < 4; i++)
    qv[i] = *(const float4*)(q_w + (size_t)dp * Dd + lane * 4 + 256 * i);
  float qb = q_b[dp];
#pragma unroll 2
  for (int bb = 0; bb < 8; bb++) {
    int b = wave * 8 + bb;
    const float* cls = tok2d + (size_t)b * TOKSTRIDE;
    float a = 0.f;
#pragma unroll
    for (int i = 0; i < 4; i++) {
      float4 cv = *(const float4*)(cls + lane * 4 + 256 * i);
      a += qv[i].x * cv.x + qv[i].y * cv.y + qv[i].z * cv.z + qv[i].w * cv.w;
    }
    a = wave_sum_dpp(a);
    if (lane == 63) batch_base(outb, b)[QC_OFF + dp] = a + qb;
  }
}

// ---------------------------------------------------------------------------
// K5'' (fused u_part + combine_ut, full-chip): grid 256 = (b:32) x (slice:8).
//     Block (b,s): u[b][s*128 .. s*128+127] = sum_dp qcls[b][dp]*v_w[dp][d].
//     Threads = 8 dp-groups x 32 d-lanes (float4). Each group g accumulates
//     over dp in [g*128,(g+1)*128) ascending — exactly the old UP[c] chunk —
//     then 32 lanes left-fold the 8 partials in ascending-g order — exactly
//     the old combine loop. Bitwise-identical u; no UP global round-trip.
//     t replicated verbatim in slice-0 blocks.
// ---------------------------------------------------------------------------
__global__ __launch_bounds__(256) void u_t_kernel(const float* __restrict__ v_w,
                                                  const float* __restrict__ v_b,
                                                  float* __restrict__ outb) {
  int b = blockIdx.x >> 3;
  int s = blockIdx.x & 7;
  int tid = threadIdx.x;
  int dl = tid & 31;   // d float4-lane within slice
  int g = tid >> 5;    // dp-group (== old chunk c)
  float* basef = batch_base(outb, b);
  __shared__ float qs[Dd];
  __shared__ float4 part[8][32];
  __shared__ float sh[256];
  for (int i = tid; i < Dd; i += 256) qs[i] = basef[QC_OFF + i];
  __syncthreads();
  int d0 = s * 128 + dl * 4;
  float4 a = make_float4(0.f, 0.f, 0.f, 0.f);
#pragma unroll 4
  for (int dpl = 0; dpl < 128; dpl++) {
    int dp = g * 128 + dpl;
    float4 vv = *(const float4*)(v_w + (size_t)dp * Dd + d0);
    float qq = qs[dp];
    a.x += qq * vv.x; a.y += qq * vv.y; a.z += qq * vv.z; a.w += qq * vv.w;
  }
  part[g][dl] = a;
  __syncthreads();
  if (tid < 32) {
    // left-fold ascending g — identical FP order to combine_ut's c-loop
    float4 u = make_float4(0.f, 0.f, 0.f, 0.f);
#pragma unroll
    for (int c = 0; c < 8; c++) {
      float4 v = part[c][tid];
      u.x += v.x; u.y += v.y; u.z += v.z; u.w += v.w;
    }
    *(float4*)(basef + U_OFF + s * 128 + tid * 4) = u;
  }

  if (s == 0) {  // t, verbatim combine_ut pattern (block-uniform branch)
    float aa = 0.f;
    for (int i = tid; i < Dd; i += 256) aa += qs[i] * v_b[i];
    sh[tid] = aa;
    __syncthreads();
    for (int st = 128; st > 0; st >>= 1) {
      if (tid < st) sh[tid] += sh[tid + st];
      __syncthreads();
    }
    if (tid == 0) basef[T_OFF] = sh[0];
  }
}

// ---------------------------------------------------------------------------
// K1 v7: fused affinity + p. v7 change: QUARTET tiling — block = (b, y, 4
//     x's); grid 4608 (2x r6's 2304). Per-token computation graph unchanged
//     (same window cols, FMA order, DPP reduction, finalize order) ->
//     bitwise-identical. Rationale: r6/r8 K1 is latency-bound (VALU 49%,
//     HBM 10%, ~8 resident waves/CU) — halving per-block work (18 vs 30
//     window loads/thread, half the DPP chains, cc[4] not cc[8]) doubles the
//     supply of independent blocks and cuts register pressure. Cost: ~20%
//     more halo/weight issue per token (FETCH +~18%, far below BW ceiling).
//     __launch_bounds__(256,3) kept (r4 lesson: never TIGHTEN the cap).
//     Watch: WRITE_SIZE >= 4 MB means spill -> revert to r8 octet.
//     XCD-bijective swizzle: 4608 = 8 * 576 contiguous ids per XCD.
// ---------------------------------------------------------------------------
__global__ __launch_bounds__(256, 3) void affinity_p_root_kernel(
    const float* __restrict__ tok2d, const float* __restrict__ dw_w,
    const float* __restrict__ pw_w, const float* __restrict__ pw_b,
    float* __restrict__ outb) {
  int wave = threadIdx.x >> 6;  // d-chunk
  int lane = threadIdx.x & 63;
  // XCD-aware bijective swizzle: 4608 blocks = 8 XCDs * 576 contiguous ids.
  int blk = (blockIdx.x & 7) * (Bb * Hh * 6 / 8) + (blockIdx.x >> 3);
  int b = blk / (Hh * 6);
  int rem = blk % (Hh * 6);
  int y = rem / 6;
  int x0 = (rem % 6) * 4;
  int d0 = wave * 256 + lane * 4;
  const float* patch = tok2d + (size_t)b * TOKSTRIDE + Dd;  // skip cls token
  float* basef = batch_base(outb, b);

  // red layout: [t:0..3][r:0..15][o:0..9], linear idx = t*167 + r*10 + o.
  // 167 (odd) pads the t-stride so finalizer lanes don't collide.
  __shared__ float red[4 * 167 + 8];

  // conv-phase registers: depthwise weights (36f) + u (4f)
  union { float4 v[9]; float f[36]; } w;
  const float4* dwp = (const float4*)(dw_w + (size_t)d0 * 9);
#pragma unroll
  for (int j = 0; j < 9; j++) w.v[j] = dwp[j];
  float4 u4 = *(const float4*)(basef + U_OFF + d0);

  // --- depthwise conv: per input row, batch-load 6-wide window, then FMA ---
  float4 cc[4];
  float pacc[4];
#pragma unroll
  for (int t = 0; t < 4; t++) {
    cc[t] = make_float4(0.f, 0.f, 0.f, 0.f);
    pacc[t] = 0.f;
  }
#pragma unroll
  for (int ky = 0; ky < 3; ky++) {
    int yy = y + ky - 1;
    if (yy < 0 || yy >= Hh) continue;  // wave-uniform (zero padding)
    const float* prow = patch + (size_t)(yy * Ww) * Dd + d0;
    float4 wrow[6];  // cols x0-1 .. x0+4; all indices compile-time (regs)
    wrow[0] = make_float4(0.f, 0.f, 0.f, 0.f);
    if (x0 > 0) wrow[0] = *(const float4*)(prow + (size_t)(x0 - 1) * Dd);
#pragma unroll
    for (int j = 1; j < 5; j++)
      wrow[j] = *(const float4*)(prow + (size_t)(x0 - 1 + j) * Dd);
    wrow[5] = make_float4(0.f, 0.f, 0.f, 0.f);
    if (x0 + 4 < Ww) wrow[5] = *(const float4*)(prow + (size_t)(x0 + 4) * Dd);
    int kA = ky * 3, kB = ky * 3 + 1, kC = ky * 3 + 2;
#pragma unroll
    for (int t = 0; t < 4; t++) {
      cc[t].x += wrow[t].x * w.f[kA] + wrow[t + 1].x * w.f[kB] +
                 wrow[t + 2].x * w.f[kC];
      cc[t].y += wrow[t].y * w.f[9 + kA] + wrow[t + 1].y * w.f[9 + kB] +
                 wrow[t + 2].y * w.f[9 + kC];
      cc[t].z += wrow[t].z * w.f[18 + kA] + wrow[t + 1].z * w.f[18 + kB] +
                 wrow[t + 2].z * w.f[18 + kC];
      cc[t].w += wrow[t].w * w.f[27 + kA] + wrow[t + 1].w * w.f[27 + kB] +
                 wrow[t + 2].w * w.f[27 + kC];
      if (ky == 1)  // middle row: wrow[t+1] is token t's center -> p partial
        pacc[t] = wrow[t + 1].x * u4.x + wrow[t + 1].y * u4.y +
                  wrow[t + 1].z * u4.z + wrow[t + 1].w * u4.w;
    }
  }

  // fence: keep pw loads out of the conv region (two-phase VGPR liveness)
  __builtin_amdgcn_sched_barrier(0);

  // pointwise-phase registers: pw (36f); dw/u now dead
  float4 pw[9];
#pragma unroll
  for (int o = 0; o < 9; o++)
    pw[o] = *(const float4*)(pw_w + (size_t)o * Dd + d0);

  // --- per-token pointwise logits + 4-stage DPP row reduction ---
#pragma unroll
  for (int t = 0; t < 4; t++) {
    float acc[10];
#pragma unroll
    for (int o = 0; o < 9; o++) {
      acc[o] = cc[t].x * pw[o].x + cc[t].y * pw[o].y + cc[t].z * pw[o].z +
               cc[t].w * pw[o].w;
    }
    acc[9] = pacc[t];
#pragma unroll
    for (int o = 0; o < 10; o++) acc[o] = row_sum_dpp(acc[o]);
    if ((lane & 15) == 15) {
      int r = wave * 4 + (lane >> 4);
#pragma unroll
      for (int o = 0; o < 10; o++) red[t * 167 + r * 10 + o] = acc[o];
    }
  }
  __syncthreads();

  // --- finalize: 1 lane per wave, token t = wave ---
  if (lane == 0) {
    int t = wave;
    int x = x0 + t;
    int n = y * Ww + x;
    float l[10];
#pragma unroll
    for (int o = 0; o < 10; o++) l[o] = 0.f;
    for (int r = 0; r < 16; r++) {
#pragma unroll
      for (int o = 0; o < 10; o++) l[o] += red[t * 167 + r * 10 + o];
    }
    float q[9];
    float mx = -INFINITY;
#pragma unroll
    for (int o = 0; o < 9; o++) {
      l[o] += pw_b[o];
      mx = fmaxf(mx, l[o]);
    }
    float ssum = 0.f;
#pragma unroll
    for (int o = 0; o < 9; o++) {
      q[o] = expf(l[o] - mx);
      ssum += q[o];
    }
#pragma unroll
    for (int o = 0; o < 9; o++) q[o] = q[o] / ssum;

    // static clipped-neighbor columns (all indices compile-time under unroll)
    int colv[9];
#pragma unroll
    for (int o = 0; o < 9; o++) {
      int dy = o / 3 - 1, dx = o % 3 - 1;
      int ny = min(max(y + dy, 0), Hh - 1);
      int nx = min(max(x + dx, 0), Ww - 1);
      colv[o] = ny * Ww + nx;
    }
    // duplicate-accumulate + argmax, tie -> lowest column. For each o the
    // column value is built in ascending-o' order (matches scatter-add).
    float best = -1.f;
    int bcol = 1 << 30;
#pragma unroll
    for (int o = 0; o < 9; o++) {
      float v = 0.f;
#pragma unroll
      for (int oo = 0; oo < 9; oo++)
        v = (colv[oo] == colv[o]) ? v + q[oo] : v;
      if (v > best || (v == best && colv[o] < bcol)) {
        best = v;
        bcol = colv[o];
      }
    }
    ((int*)basef)[R0_OFF + n] = bcol;
    basef[P_OFF + n] = l[9];
  }
}

// ---------------------------------------------------------------------------
// K2' (fused cluster_topk + scores_plan): 6x pointer jumping + counts +
//     stable counting sort + top-256 (exact top_k ties) + scores + top-128 +
//     plan write — all in one 576-thread block per batch. Members, offsets,
//     ord/cnt and P all stay in LDS; no MEMB/OFFS/ORD/CNT global round-trip.
// ---------------------------------------------------------------------------
__global__ __launch_bounds__(576) void cluster_scores_plan_kernel(
    float* __restrict__ outb) {
  int b = blockIdx.x;
  int n = threadIdx.x;
  float* basef = batch_base(outb, b);
  int* base = (int*)basef;
  __shared__ int ra[Nn], rb2[Nn], scnt[Nn], soff[Nn], smem[Nn];
  __shared__ float sp[Nn];
  __shared__ int s_ord[Kk], s_cnt[Kk], sel[Kk], s_out[Mm];
  __shared__ float ss[Kk];
  ra[n] = base[R0_OFF + n];
  sp[n] = basef[P_OFF + n];
  scnt[n] = 0;
  __syncthreads();
  for (int it = 0; it < 6; it++) {
    rb2[n] = ra[ra[n]];
    __syncthreads();
    ra[n] = rb2[n];
    __syncthreads();
  }
  int r = ra[n];
  atomicAdd(&scnt[r], 1);
  __syncthreads();

  // inclusive scan of scnt -> soff
  soff[n] = scnt[n];
  __syncthreads();
  for (int s = 1; s < Nn; s <<= 1) {
    int v = (n >= s) ? soff[n - s] : 0;
    __syncthreads();
    soff[n] += v;
    __syncthreads();
  }
  // stable counting sort into LDS member list
  int offr = soff[r] - scnt[r];
  int rk = 0;
  for (int m = 0; m < n; m++) rk += (ra[m] == r);
  smem[offr + rk] = n;

  // --- top-256 of counts (value desc, index asc), ascending-index output ---
  int cn = scnt[n];
  int rank = 0;
  for (int m = 0; m < Nn; m++) {
    int cm = scnt[m];
    rank += (cm > cn) || (cm == cn && m < n);
  }
  int sl = (rank < Kk) ? 1 : 0;
  rb2[n] = sl;
  __syncthreads();
  for (int s = 1; s < Nn; s <<= 1) {
    int v = (n >= s) ? rb2[n - s] : 0;
    __syncthreads();
    rb2[n] += v;
    __syncthreads();
  }
  if (sl) {
    int pos = rb2[n] - 1;
    s_ord[pos] = n;
    s_cnt[pos] = cn;
  }
  __syncthreads();  // smem + s_ord/s_cnt complete

  // --- scores (first 256 threads, one selected cluster each) ---
  if (n < Kk) {
    int idx = s_ord[n];
    int c = s_cnt[n];
    float s;
    if (c > 0) {
      int off = soff[idx] - scnt[idx];
      float sum = 0.f;
      for (int j = 0; j < c; j++) sum += sp[smem[off + j]];
      s = (sum / (float)c + basef[T_OFF]) * (1.0f / 32.0f);
    } else {
      s = -INFINITY;
    }
    ss[n] = s;
  }
  __syncthreads();

  // --- top-128 (value desc, index asc), ascending-index output ---
  if (n < Kk) {
    float vk = ss[n];
    int rank2 = 0;
    for (int m = 0; m < Kk; m++) {
      float vm = ss[m];
      rank2 += (vm > vk) || (vm == vk && m < n);
    }
    sel[n] = (rank2 < Mm) ? 1 : 0;
  }
  __syncthreads();
  if (n < Kk && sel[n]) {
    int pos = 0;
    for (int m = 0; m < n; m++) pos += sel[m];
    s_out[pos] = n;
  }
  __syncthreads();

  // --- plan: write [count, member ids...] into this batch's 128 rows ---
  int w9 = n >> 6, lane = n & 63;
  for (int kp = w9; kp < Mm; kp += 9) {
    int k = s_out[kp];
    int kidx = s_ord[k];
    int kc = s_cnt[k];
    int koff = soff[kidx] - scnt[kidx];
    int* row = base + kp * Dd;
    if (lane == 0) row[0] = kc;
    for (int j = lane; j < kc; j += 64) row[1 + j] = smem[koff + j];
  }
}

// ---------------------------------------------------------------------------
// K8: output. One block per output row; reads its OWN row's plan into LDS,
//     then overwrites the row with the cluster mean. float4 over d.
// ---------------------------------------------------------------------------
__global__ __launch_bounds__(256) void output_kernel(
    const float* __restrict__ tok2d, float* __restrict__ outb) {
  int blk = blockIdx.x;  // b*Mm + kp
  int b = blk / Mm;
  int tid = threadIdx.x;
  float* rowf = outb + (size_t)blk * Dd;
  int* rowi = (int*)rowf;
  __shared__ int s_c;
  __shared__ int s_m[Nn];
  if (tid == 0) s_c = rowi[0];
  __syncthreads();
  int c = s_c;
  for (int j = tid; j < c; j += 256) s_m[j] = rowi[1 + j];
  __syncthreads();
  const float* patch = tok2d + (size_t)b * TOKSTRIDE + Dd;
  int d0 = tid * 4;
  float4 acc = make_float4(0.f, 0.f, 0.f, 0.f);
  for (int j = 0; j < c; j++) {
    float4 rv = *(const float4*)(patch + (size_t)s_m[j] * Dd + d0);
    acc.x += rv.x; acc.y += rv.y; acc.z += rv.z; acc.w += rv.w;
  }
  float inv = 1.0f / (float)max(c, 1);
  *(float4*)(rowf + d0) =
      make_float4(acc.x * inv, acc.y * inv, acc.z * inv, acc.w * inv);
}

// ---------------------------------------------------------------------------
extern "C" void kernel_launch(void* const* d_in, const int* in_sizes, int n_in,
                              void* d_out, int out_size, void* d_ws,
                              size_t ws_size, hipStream_t stream) {
  const float* tok2d = (const float*)d_in[0];
  const float* dw_w = (const float*)d_in[1];
  const float* pw_w = (const float*)d_in[2];
  const float* pw_b = (const float*)d_in[3];
  const float* q_w = (const float*)d_in[4];
  const float* q_b = (const float*)d_in[5];
  const float* v_w = (const float*)d_in[6];
  const float* v_b = (const float*)d_in[7];
  float* out = (float*)d_out;
  (void)d_ws; (void)ws_size;  // d_ws intentionally unused

  // u/t first (affinity's fused p-dot needs u)
  qcls_kernel<<<dim3(Dd), dim3(256), 0, stream>>>(tok2d, q_w, q_b, out);
  u_t_kernel<<<dim3(Bb * 8), dim3(256), 0, stream>>>(v_w, v_b, out);
  affinity_p_root_kernel<<<dim3(Bb * Hh * 6), dim3(256), 0, stream>>>(
      tok2d, dw_w, pw_w, pw_b, out);
  cluster_scores_plan_kernel<<<dim3(Bb), dim3(Nn), 0, stream>>>(out);
  output_kernel<<<dim3(Bb * Mm), dim3(256), 0, stream>>>(tok2d, out);
}

// Round 11
// 233.427 us; speedup vs baseline: 1.3271x; 1.0333x over previous
//
#include <hip/hip_runtime.h>
#include <math.h>

#define Hh 24
#define Ww 24
#define Nn 576
#define Dd 1024
#define Bb 32
#define Kk 256
#define Mm 128
#define TOKSTRIDE (577 * 1024)

// Per-batch scratch lives INSIDE d_out: batch b owns out[b*Mm*Dd .. (b+1)*Mm*Dd).
// Scratch is consumed (via LDS/regs) before the plan/output phases overwrite
// the rows. d_ws is NOT used. (r7: cooperative launch breaks graph capture;
// r9: spin-barrier fusion costs more than the launch it saves; r10: quartet
// tiling trades +50% VALU amortization loss for occupancy — octet optimal.)
#define R0_OFF 0       // roots0           : 576 int
#define P_OFF 2944     // p = patch.u      : 576 float
#define QC_OFF 3776    // qcls             : 1024 float
#define U_OFF 4800     // u = qcls.v_w     : 1024 float
#define T_OFF 5824     // t = qcls.v_b     : 1 float

__device__ __forceinline__ float* batch_base(float* out, int b) {
  return out + (size_t)b * Mm * Dd;
}

// Full-wave (64-lane) float sum via DPP — VALU pipe only, no LDS traffic.
// Canonical gfx9/CDNA sequence; result valid in lane 63.
__device__ __forceinline__ float wave_sum_dpp(float x) {
  int y;
  y = __builtin_amdgcn_update_dpp(0, __float_as_int(x), 0x111, 0xf, 0xf, true);
  x += __int_as_float(y);  // row_shr:1
  y = __builtin_amdgcn_update_dpp(0, __float_as_int(x), 0x112, 0xf, 0xf, true);
  x += __int_as_float(y);  // row_shr:2
  y = __builtin_amdgcn_update_dpp(0, __float_as_int(x), 0x114, 0xf, 0xf, true);
  x += __int_as_float(y);  // row_shr:4
  y = __builtin_amdgcn_update_dpp(0, __float_as_int(x), 0x118, 0xf, 0xf, true);
  x += __int_as_float(y);  // row_shr:8  -> lanes 15/31/47/63 hold row sums
  y = __builtin_amdgcn_update_dpp(0, __float_as_int(x), 0x142, 0xa, 0xf, true);
  x += __int_as_float(y);  // row_bcast:15 into rows 1,3
  y = __builtin_amdgcn_update_dpp(0, __float_as_int(x), 0x143, 0xc, 0xf, true);
  x += __int_as_float(y);  // row_bcast:31 into rows 2,3 -> lane 63 = total
  return x;
}

// 16-lane row sum via DPP (4 stages). Lanes 15/31/47/63 hold their row's sum.
__device__ __forceinline__ float row_sum_dpp(float x) {
  int y;
  y = __builtin_amdgcn_update_dpp(0, __float_as_int(x), 0x111, 0xf, 0xf, true);
  x += __int_as_float(y);  // row_shr:1
  y = __builtin_amdgcn_update_dpp(0, __float_as_int(x), 0x112, 0xf, 0xf, true);
  x += __int_as_float(y);  // row_shr:2
  y = __builtin_amdgcn_update_dpp(0, __float_as_int(x), 0x114, 0xf, 0xf, true);
  x += __int_as_float(y);  // row_shr:4
  y = __builtin_amdgcn_update_dpp(0, __float_as_int(x), 0x118, 0xf, 0xf, true);
  x += __int_as_float(y);  // row_shr:8
  return x;
}

// ---------------------------------------------------------------------------
// K4 (runs FIRST): qcls[b,dp] = cls[b]·q_w[dp,:] + q_b[dp]. One block per dp;
//     4 waves, each handles 8 batches (q_w row reused in regs). r7 lesson:
//     this 4096-wave geometry is 4x the coop variant's parallelism — keep it.
// ---------------------------------------------------------------------------
__global__ __launch_bounds__(256) void qcls_kernel(
    const float* __restrict__ tok2d, const float* __restrict__ q_w,
    const float* __restrict__ q_b, float* __restrict__ outb) {
  int dp = blockIdx.x;
  int wave = threadIdx.x >> 6;
  int lane = threadIdx.x & 63;
  float4 qv[4];
#pragma unroll
  for (int i = 0; i < 4; i++)
    qv[i] = *(const float4*)(q_w + (size_t)dp * Dd + lane * 4 + 256 * i);
  float qb = q_b[dp];
#pragma unroll 2
  for (int bb = 0; bb < 8; bb++) {
    int b = wave * 8 + bb;
    const float* cls = tok2d + (size_t)b * TOKSTRIDE;
    float a = 0.f;
#pragma unroll
    for (int i = 0; i < 4; i++) {
      float4 cv = *(const float4*)(cls + lane * 4 + 256 * i);
      a += qv[i].x * cv.x + qv[i].y * cv.y + qv[i].z * cv.z + qv[i].w * cv.w;
    }
    a = wave_sum_dpp(a);
    if (lane == 63) batch_base(outb, b)[QC_OFF + dp] = a + qb;
  }
}

// ---------------------------------------------------------------------------
// K5'' (fused u_part + combine_ut, full-chip): grid 256 = (b:32) x (slice:8).
//     Block (b,s): u[b][s*128 .. s*128+127] = sum_dp qcls[b][dp]*v_w[dp][d].
//     Threads = 8 dp-groups x 32 d-lanes (float4). Each group g accumulates
//     over dp in [g*128,(g+1)*128) ascending — exactly the old UP[c] chunk —
//     then 32 lanes left-fold the 8 partials in ascending-g order — exactly
//     the old combine loop. Bitwise-identical u; no UP global round-trip.
//     t replicated verbatim in slice-0 blocks.
// ---------------------------------------------------------------------------
__global__ __launch_bounds__(256) void u_t_kernel(const float* __restrict__ v_w,
                                                  const float* __restrict__ v_b,
                                                  float* __restrict__ outb) {
  int b = blockIdx.x >> 3;
  int s = blockIdx.x & 7;
  int tid = threadIdx.x;
  int dl = tid & 31;   // d float4-lane within slice
  int g = tid >> 5;    // dp-group (== old chunk c)
  float* basef = batch_base(outb, b);
  __shared__ float qs[Dd];
  __shared__ float4 part[8][32];
  __shared__ float sh[256];
  for (int i = tid; i < Dd; i += 256) qs[i] = basef[QC_OFF + i];
  __syncthreads();
  int d0 = s * 128 + dl * 4;
  float4 a = make_float4(0.f, 0.f, 0.f, 0.f);
#pragma unroll 4
  for (int dpl = 0; dpl < 128; dpl++) {
    int dp = g * 128 + dpl;
    float4 vv = *(const float4*)(v_w + (size_t)dp * Dd + d0);
    float qq = qs[dp];
    a.x += qq * vv.x; a.y += qq * vv.y; a.z += qq * vv.z; a.w += qq * vv.w;
  }
  part[g][dl] = a;
  __syncthreads();
  if (tid < 32) {
    // left-fold ascending g — identical FP order to combine_ut's c-loop
    float4 u = make_float4(0.f, 0.f, 0.f, 0.f);
#pragma unroll
    for (int c = 0; c < 8; c++) {
      float4 v = part[c][tid];
      u.x += v.x; u.y += v.y; u.z += v.z; u.w += v.w;
    }
    *(float4*)(basef + U_OFF + s * 128 + tid * 4) = u;
  }

  if (s == 0) {  // t, verbatim combine_ut pattern (block-uniform branch)
    float aa = 0.f;
    for (int i = tid; i < Dd; i += 256) aa += qs[i] * v_b[i];
    sh[tid] = aa;
    __syncthreads();
    for (int st = 128; st > 0; st >>= 1) {
      if (tid < st) sh[tid] += sh[tid + st];
      __syncthreads();
    }
    if (tid == 0) basef[T_OFF] = sh[0];
  }
}

// ---------------------------------------------------------------------------
// K1 v6 (r6/r8 proven optimum, ~50 µs): fused affinity + p. Block = (b, y,
//     octet of 8 x's); 4 waves = 4 d-chunks of 256. Conv loads the full
//     10-wide row window into wrow[10] (independent loads back-to-back),
//     then the 8-token FMA sweep runs from registers.
//     Octet tiling is the amortization sweet spot (r10: quartet = +50% VALU
//     work from per-block weight reloads; larger tiles spill — r3/r4).
//     __launch_bounds__(256,3): VGPR 68, zero spill. Never TIGHTEN (r4).
//     Reduction: 4-stage DPP 16-lane row sums -> padded LDS; finalize 2
//     lanes x 4 waves, fixed r-order (bitwise stable).
//     XCD-bijective block swizzle (2304 = 8*288): contiguous (b,y) per XCD.
// ---------------------------------------------------------------------------
__global__ __launch_bounds__(256, 3) void affinity_p_root_kernel(
    const float* __restrict__ tok2d, const float* __restrict__ dw_w,
    const float* __restrict__ pw_w, const float* __restrict__ pw_b,
    float* __restrict__ outb) {
  int wave = threadIdx.x >> 6;  // d-chunk
  int lane = threadIdx.x & 63;
  // XCD-aware bijective swizzle: 2304 blocks = 8 XCDs * 288 contiguous ids.
  int blk = (blockIdx.x & 7) * (Bb * Hh * 3 / 8) + (blockIdx.x >> 3);
  int b = blk / (Hh * 3);
  int rem = blk % (Hh * 3);
  int y = rem / 3;
  int x0 = (rem % 3) * 8;
  int d0 = wave * 256 + lane * 4;
  const float* patch = tok2d + (size_t)b * TOKSTRIDE + Dd;  // skip cls token
  float* basef = batch_base(outb, b);

  // red layout: [t:0..7][r:0..15][o:0..9], linear idx = t*167 + r*10 + o.
  // 167 (odd, %32==7) pads the t-stride so finalizer lanes don't collide.
  __shared__ float red[8 * 167 + 8];

  // conv-phase registers: depthwise weights (36f) + u (4f)
  union { float4 v[9]; float f[36]; } w;
  const float4* dwp = (const float4*)(dw_w + (size_t)d0 * 9);
#pragma unroll
  for (int j = 0; j < 9; j++) w.v[j] = dwp[j];
  float4 u4 = *(const float4*)(basef + U_OFF + d0);

  // --- depthwise conv: per input row, batch-load 10-wide window, then FMA ---
  float4 cc[8];
  float pacc[8];
#pragma unroll
  for (int t = 0; t < 8; t++) {
    cc[t] = make_float4(0.f, 0.f, 0.f, 0.f);
    pacc[t] = 0.f;
  }
#pragma unroll
  for (int ky = 0; ky < 3; ky++) {
    int yy = y + ky - 1;
    if (yy < 0 || yy >= Hh) continue;  // wave-uniform (zero padding)
    const float* prow = patch + (size_t)(yy * Ww) * Dd + d0;
    float4 wrow[10];  // cols x0-1 .. x0+8; all indices compile-time (regs)
    wrow[0] = make_float4(0.f, 0.f, 0.f, 0.f);
    if (x0 > 0) wrow[0] = *(const float4*)(prow + (size_t)(x0 - 1) * Dd);
#pragma unroll
    for (int j = 1; j < 9; j++)
      wrow[j] = *(const float4*)(prow + (size_t)(x0 - 1 + j) * Dd);
    wrow[9] = make_float4(0.f, 0.f, 0.f, 0.f);
    if (x0 + 8 < Ww) wrow[9] = *(const float4*)(prow + (size_t)(x0 + 8) * Dd);
    int kA = ky * 3, kB = ky * 3 + 1, kC = ky * 3 + 2;
#pragma unroll
    for (int t = 0; t < 8; t++) {
      cc[t].x += wrow[t].x * w.f[kA] + wrow[t + 1].x * w.f[kB] +
                 wrow[t + 2].x * w.f[kC];
      cc[t].y += wrow[t].y * w.f[9 + kA] + wrow[t + 1].y * w.f[9 + kB] +
                 wrow[t + 2].y * w.f[9 + kC];
      cc[t].z += wrow[t].z * w.f[18 + kA] + wrow[t + 1].z * w.f[18 + kB] +
                 wrow[t + 2].z * w.f[18 + kC];
      cc[t].w += wrow[t].w * w.f[27 + kA] + wrow[t + 1].w * w.f[27 + kB] +
                 wrow[t + 2].w * w.f[27 + kC];
      if (ky == 1)  // middle row: wrow[t+1] is token t's center -> p partial
        pacc[t] = wrow[t + 1].x * u4.x + wrow[t + 1].y * u4.y +
                  wrow[t + 1].z * u4.z + wrow[t + 1].w * u4.w;
    }
  }

  // fence: keep pw loads out of the conv region (two-phase VGPR liveness)
  __builtin_amdgcn_sched_barrier(0);

  // pointwise-phase registers: pw (36f); dw/u now dead
  float4 pw[9];
#pragma unroll
  for (int o = 0; o < 9; o++)
    pw[o] = *(const float4*)(pw_w + (size_t)o * Dd + d0);

  // --- per-token pointwise logits + 4-stage DPP row reduction ---
#pragma unroll
  for (int t = 0; t < 8; t++) {
    float acc[10];
#pragma unroll
    for (int o = 0; o < 9; o++) {
      acc[o] = cc[t].x * pw[o].x + cc[t].y * pw[o].y + cc[t].z * pw[o].z +
               cc[t].w * pw[o].w;
    }
    acc[9] = pacc[t];
#pragma unroll
    for (int o = 0; o < 10; o++) acc[o] = row_sum_dpp(acc[o]);
    if ((lane & 15) == 15) {
      int r = wave * 4 + (lane >> 4);
#pragma unroll
      for (int o = 0; o < 10; o++) red[t * 167 + r * 10 + o] = acc[o];
    }
  }
  __syncthreads();

  // --- finalize: 2 lanes per wave, token t = wave*2 + lane ---
  if (lane < 2) {
    int t = wave * 2 + lane;
    int x = x0 + t;
    int n = y * Ww + x;
    float l[10];
#pragma unroll
    for (int o = 0; o < 10; o++) l[o] = 0.f;
    for (int r = 0; r < 16; r++) {
#pragma unroll
      for (int o = 0; o < 10; o++) l[o] += red[t * 167 + r * 10 + o];
    }
    float q[9];
    float mx = -INFINITY;
#pragma unroll
    for (int o = 0; o < 9; o++) {
      l[o] += pw_b[o];
      mx = fmaxf(mx, l[o]);
    }
    float ssum = 0.f;
#pragma unroll
    for (int o = 0; o < 9; o++) {
      q[o] = expf(l[o] - mx);
      ssum += q[o];
    }
#pragma unroll
    for (int o = 0; o < 9; o++) q[o] = q[o] / ssum;

    // static clipped-neighbor columns (all indices compile-time under unroll)
    int colv[9];
#pragma unroll
    for (int o = 0; o < 9; o++) {
      int dy = o / 3 - 1, dx = o % 3 - 1;
      int ny = min(max(y + dy, 0), Hh - 1);
      int nx = min(max(x + dx, 0), Ww - 1);
      colv[o] = ny * Ww + nx;
    }
    // duplicate-accumulate + argmax, tie -> lowest column. For each o the
    // column value is built in ascending-o' order (matches scatter-add).
    float best = -1.f;
    int bcol = 1 << 30;
#pragma unroll
    for (int o = 0; o < 9; o++) {
      float v = 0.f;
#pragma unroll
      for (int oo = 0; oo < 9; oo++)
        v = (colv[oo] == colv[o]) ? v + q[oo] : v;
      if (v > best || (v == best && colv[o] < bcol)) {
        best = v;
        bcol = colv[o];
      }
    }
    ((int*)basef)[R0_OFF + n] = bcol;
    basef[P_OFF + n] = l[9];
  }
}

// ---------------------------------------------------------------------------
// K2' (fused cluster_topk + scores_plan): 6x pointer jumping + counts +
//     stable counting sort + top-256 (exact top_k ties) + scores + top-128 +
//     plan write — all in one 576-thread block per batch. Members, offsets,
//     ord/cnt and P all stay in LDS; no MEMB/OFFS/ORD/CNT global round-trip.
// ---------------------------------------------------------------------------
__global__ __launch_bounds__(576) void cluster_scores_plan_kernel(
    float* __restrict__ outb) {
  int b = blockIdx.x;
  int n = threadIdx.x;
  float* basef = batch_base(outb, b);
  int* base = (int*)basef;
  __shared__ int ra[Nn], rb2[Nn], scnt[Nn], soff[Nn], smem[Nn];
  __shared__ float sp[Nn];
  __shared__ int s_ord[Kk], s_cnt[Kk], sel[Kk], s_out[Mm];
  __shared__ float ss[Kk];
  ra[n] = base[R0_OFF + n];
  sp[n] = basef[P_OFF + n];
  scnt[n] = 0;
  __syncthreads();
  for (int it = 0; it < 6; it++) {
    rb2[n] = ra[ra[n]];
    __syncthreads();
    ra[n] = rb2[n];
    __syncthreads();
  }
  int r = ra[n];
  atomicAdd(&scnt[r], 1);
  __syncthreads();

  // inclusive scan of scnt -> soff
  soff[n] = scnt[n];
  __syncthreads();
  for (int s = 1; s < Nn; s <<= 1) {
    int v = (n >= s) ? soff[n - s] : 0;
    __syncthreads();
    soff[n] += v;
    __syncthreads();
  }
  // stable counting sort into LDS member list
  int offr = soff[r] - scnt[r];
  int rk = 0;
  for (int m = 0; m < n; m++) rk += (ra[m] == r);
  smem[offr + rk] = n;

  // --- top-256 of counts (value desc, index asc), ascending-index output ---
  int cn = scnt[n];
  int rank = 0;
  for (int m = 0; m < Nn; m++) {
    int cm = scnt[m];
    rank += (cm > cn) || (cm == cn && m < n);
  }
  int sl = (rank < Kk) ? 1 : 0;
  rb2[n] = sl;
  __syncthreads();
  for (int s = 1; s < Nn; s <<= 1) {
    int v = (n >= s) ? rb2[n - s] : 0;
    __syncthreads();
    rb2[n] += v;
    __syncthreads();
  }
  if (sl) {
    int pos = rb2[n] - 1;
    s_ord[pos] = n;
    s_cnt[pos] = cn;
  }
  __syncthreads();  // smem + s_ord/s_cnt complete

  // --- scores (first 256 threads, one selected cluster each) ---
  if (n < Kk) {
    int idx = s_ord[n];
    int c = s_cnt[n];
    float s;
    if (c > 0) {
      int off = soff[idx] - scnt[idx];
      float sum = 0.f;
      for (int j = 0; j < c; j++) sum += sp[smem[off + j]];
      s = (sum / (float)c + basef[T_OFF]) * (1.0f / 32.0f);
    } else {
      s = -INFINITY;
    }
    ss[n] = s;
  }
  __syncthreads();

  // --- top-128 (value desc, index asc), ascending-index output ---
  if (n < Kk) {
    float vk = ss[n];
    int rank2 = 0;
    for (int m = 0; m < Kk; m++) {
      float vm = ss[m];
      rank2 += (vm > vk) || (vm == vk && m < n);
    }
    sel[n] = (rank2 < Mm) ? 1 : 0;
  }
  __syncthreads();
  if (n < Kk && sel[n]) {
    int pos = 0;
    for (int m = 0; m < n; m++) pos += sel[m];
    s_out[pos] = n;
  }
  __syncthreads();

  // --- plan: write [count, member ids...] into this batch's 128 rows ---
  int w9 = n >> 6, lane = n & 63;
  for (int kp = w9; kp < Mm; kp += 9) {
    int k = s_out[kp];
    int kidx = s_ord[k];
    int kc = s_cnt[k];
    int koff = soff[kidx] - scnt[kidx];
    int* row = base + kp * Dd;
    if (lane == 0) row[0] = kc;
    for (int j = lane; j < kc; j += 64) row[1 + j] = smem[koff + j];
  }
}

// ---------------------------------------------------------------------------
// K8: output. One block per output row; reads its OWN row's plan into LDS,
//     then overwrites the row with the cluster mean. float4 over d.
// ---------------------------------------------------------------------------
__global__ __launch_bounds__(256) void output_kernel(
    const float* __restrict__ tok2d, float* __restrict__ outb) {
  int blk = blockIdx.x;  // b*Mm + kp
  int b = blk / Mm;
  int tid = threadIdx.x;
  float* rowf = outb + (size_t)blk * Dd;
  int* rowi = (int*)rowf;
  __shared__ int s_c;
  __shared__ int s_m[Nn];
  if (tid == 0) s_c = rowi[0];
  __syncthreads();
  int c = s_c;
  for (int j = tid; j < c; j += 256) s_m[j] = rowi[1 + j];
  __syncthreads();
  const float* patch = tok2d + (size_t)b * TOKSTRIDE + Dd;
  int d0 = tid * 4;
  float4 acc = make_float4(0.f, 0.f, 0.f, 0.f);
  for (int j = 0; j < c; j++) {
    float4 rv = *(const float4*)(patch + (size_t)s_m[j] * Dd + d0);
    acc.x += rv.x; acc.y += rv.y; acc.z += rv.z; acc.w += rv.w;
  }
  float inv = 1.0f / (float)max(c, 1);
  *(float4*)(rowf + d0) =
      make_float4(acc.x * inv, acc.y * inv, acc.z * inv, acc.w * inv);
}

// ---------------------------------------------------------------------------
extern "C" void kernel_launch(void* const* d_in, const int* in_sizes, int n_in,
                              void* d_out, int out_size, void* d_ws,
                              size_t ws_size, hipStream_t stream) {
  const float* tok2d = (const float*)d_in[0];
  const float* dw_w = (const float*)d_in[1];
  const float* pw_w = (const float*)d_in[2];
  const float* pw_b = (const float*)d_in[3];
  const float* q_w = (const float*)d_in[4];
  const float* q_b = (const float*)d_in[5];
  const float* v_w = (const float*)d_in[6];
  const float* v_b = (const float*)d_in[7];
  float* out = (float*)d_out;
  (void)d_ws; (void)ws_size;  // d_ws intentionally unused

  // u/t first (affinity's fused p-dot needs u)
  qcls_kernel<<<dim3(Dd), dim3(256), 0, stream>>>(tok2d, q_w, q_b, out);
  u_t_kernel<<<dim3(Bb * 8), dim3(256), 0, stream>>>(v_w, v_b, out);
  affinity_p_root_kernel<<<dim3(Bb * Hh * 3), dim3(256), 0, stream>>>(
      tok2d, dw_w, pw_w, pw_b, out);
  cluster_scores_plan_kernel<<<dim3(Bb), dim3(Nn), 0, stream>>>(out);
  output_kernel<<<dim3(Bb * Mm), dim3(256), 0, stream>>>(tok2d, out);
}